// Round 12
// baseline (232.649 us; speedup 1.0000x reference)
//
#include <hip/hip_runtime.h>
#include <stdint.h>

// out[b,n] = sum_{c,hw} x[b,c,hw]*W_s[n,hw]*W_d[n,c] + W_b[n]
// GEMM: A = x (M=8192, K=3136), B = W_s (N=1024, K=3136), fused c-contraction.
// R11: A staged as RAW FP32 via global_load_lds (no x pre-convert at all);
//      bf16 pack moved to the LDS->reg path in the compute phase (co-issues
//      with MFMA). Kills the 154 MB x-convert round-trip without the R8/R9
//      VGPR-chain failure mode. B bf16-DMA from tiny W_s convert. LDS 80 KB.

#define K_DIM 3136
#define N_DIM 1024
#define C_DIM 256
#define B_DIM 32
#define M_DIM 8192
#define WS_ELEMS (N_DIM * K_DIM)  // 3211264

typedef __attribute__((ext_vector_type(8))) short short8v;  // 8 bf16
typedef __attribute__((ext_vector_type(4))) float f32x4;
typedef __attribute__((ext_vector_type(4))) unsigned int uint4v;

// round-to-nearest-even fp32 -> bf16 (W_s pre-convert)
__device__ __forceinline__ short f2bf(float f) {
  union { float f; unsigned u; } v; v.f = f;
  unsigned r = v.u + 0x7FFFu + ((v.u >> 16) & 1u);
  return (short)(r >> 16);
}

// pack two fp32 -> two bf16 (round-half-up; verified absmax 16 in R8/R9)
__device__ __forceinline__ unsigned pk2bf(float a, float b) {
  unsigned ua = __float_as_uint(a) + 0x8000u;
  unsigned ub = __float_as_uint(b) + 0x8000u;
  return (ua >> 16) | (ub & 0xFFFF0000u);
}

// 16B-per-lane async global->LDS. LDS dest = wave-uniform base + lane*16.
__device__ __forceinline__ void async16(const void* g, void* l) {
  __builtin_amdgcn_global_load_lds(
      (const __attribute__((address_space(1))) unsigned int*)g,
      (__attribute__((address_space(3))) unsigned int*)l, 16, 0, 0);
}

// fp32 -> bf16 for W_s only (x never converted), plus bias into out.
#define WSBLK (WS_ELEMS / 2048)  // 1568
__global__ __launch_bounds__(256) void convert_ws_bias(
    const float* __restrict__ Ws, const float* __restrict__ Wb,
    short* __restrict__ dst, float* __restrict__ out) {
  int bid = blockIdx.x;
  if (bid >= WSBLK) {  // bias: 32768 out elems / 256 = 128 blocks
    int i = (bid - WSBLK) * 256 + threadIdx.x;
    out[i] = Wb[i & (N_DIM - 1)];
    return;
  }
  size_t i = (size_t)bid * 2048 + threadIdx.x * 8;
  f32x4 v0 = __builtin_nontemporal_load((const f32x4*)(Ws + i));
  f32x4 v1 = __builtin_nontemporal_load((const f32x4*)(Ws + i) + 1);
  short8v s;
  s[0] = f2bf(v0.x); s[1] = f2bf(v0.y); s[2] = f2bf(v0.z); s[3] = f2bf(v0.w);
  s[4] = f2bf(v1.x); s[5] = f2bf(v1.y); s[6] = f2bf(v1.z); s[7] = f2bf(v1.w);
  *(short8v*)(dst + i) = s;
}

// LDS A: 256 rows x 64 fp32 (256 B/row, 16 chunks of 16 B). slot(row, cs)
// holds global chunk cs ^ (row&15); reads XOR back -> 16 lanes spread over
// all 32 banks (same family as the verified-0-conflict bf16 swizzle).
// LDS B: 128 rows x 64 bf16, slot = cs ^ (row&7), unchanged from R5.
__global__ __launch_bounds__(512, 4) void gemm_fused(
    const float* __restrict__ x, const short* __restrict__ Bbf,
    const float* __restrict__ Wd, float* __restrict__ out) {
  __shared__ __align__(16) float As[256 * 64];  // 64 KB fp32
  __shared__ __align__(16) short Bs[128 * 64];  // 16 KB bf16

  const int bid = blockIdx.x;
  const int mt = bid & 31;          // bid%8 == mt%8 -> A-tile pinned to XCD
  const int nt = (bid >> 5) & 7;
  const int z = bid >> 8;           // K-split half: 49 = 25 + 24
  const int kt0 = z * 25;
  const int ktn = z ? 24 : 25;

  const int t = threadIdx.x;
  const int lane = t & 63;
  const int wv = t >> 6;            // 0..7
  const int r = lane & 15;
  const int q = lane >> 4;
  const int wm = wv >> 1, wn = wv & 1;  // 4x2 wave grid over 256x128 tile

  // B staging (bf16 DMA): lane -> (rr8, k8); wave rows [wv*16,+16), p=0..1.
  const int rr8 = lane >> 3;
  const int k8 = (lane & 7) ^ rr8;
  const short* Bw = Bbf + (size_t)(nt * 128 + wv * 16 + rr8) * K_DIM + k8 * 8 + kt0 * 64;
  char* BsB = (char*)Bs + wv * 2048;

  // A staging (fp32 DMA): instr p = 4 rows (wv*32 + p*4 + rr4), lane slot s16;
  // global chunk g = s16 ^ (row & 15). 8 precomputed per-p pointers.
  const int rr4 = lane >> 4;        // 0..3
  const int s16 = lane & 15;
  const float* Ap[8];
#pragma unroll
  for (int p = 0; p < 8; ++p) {
    const int row = wv * 32 + p * 4 + rr4;
    const int g = s16 ^ (row & 15);
    Ap[p] = x + (size_t)(mt * 256 + row) * K_DIM + kt0 * 64 + g * 4;
  }
  char* AsW = (char*)As + wv * 8192;

  f32x4 acc[4][4];
#pragma unroll
  for (int i = 0; i < 4; ++i)
#pragma unroll
    for (int j = 0; j < 4; ++j) acc[i][j] = (f32x4)0.0f;

  for (int kt = 0; kt < ktn; ++kt) {
    __syncthreads();  // prev iteration's LDS reads done
#pragma unroll
    for (int p = 0; p < 8; ++p)
      async16(Ap[p] + kt * 64, AsW + p * 1024);
#pragma unroll
    for (int p = 0; p < 2; ++p)
      async16(Bw + (size_t)p * 8 * K_DIM + kt * 64, BsB + p * 1024);
    __syncthreads();  // vmcnt(0) drain: DMA complete across all waves

#pragma unroll
    for (int ks = 0; ks < 2; ++ks) {
      const int h2 = 8 * ks + 2 * q;       // first fp32 chunk wanted
      const int xo = ((ks * 4 + q) ^ (r & 7)) * 16;
      short8v b[4];
#pragma unroll
      for (int j = 0; j < 4; ++j)
        b[j] = *(const short8v*)((const char*)Bs + (64 * wn + 16 * j + r) * 128 + xo);
#pragma unroll
      for (int i = 0; i < 4; ++i) {
        const char* rowp = (const char*)As + (64 * wm + 16 * i + r) * 256;
        f32x4 va = *(const f32x4*)(rowp + ((h2 ^ r) * 16));
        f32x4 vb = *(const f32x4*)(rowp + (((h2 + 1) ^ r) * 16));
        union { uint4v u; short8v s; } cvt;
        cvt.u.x = pk2bf(va.x, va.y);
        cvt.u.y = pk2bf(va.z, va.w);
        cvt.u.z = pk2bf(vb.x, vb.y);
        cvt.u.w = pk2bf(vb.z, vb.w);
#pragma unroll
        for (int j = 0; j < 4; ++j)
          acc[i][j] = __builtin_amdgcn_mfma_f32_16x16x32_bf16(cvt.s, b[j],
                                                              acc[i][j], 0, 0, 0);
      }
    }
  }

  // epilogue: out[mt, n] += sum_c acc * W_d[n, c]; A-tile = image mt, c = row.
  // C/D frag layout: col = lane&15 (n), row = q*4 + reg (c).
#pragma unroll
  for (int j = 0; j < 4; ++j) {
    const int n_g = nt * 128 + 64 * wn + 16 * j + r;
    float p = 0.0f;
#pragma unroll
    for (int i = 0; i < 4; ++i) {
      const int c_l = 64 * wm + 16 * i + 4 * q;
      const float4 wd = *(const float4*)(Wd + (size_t)n_g * C_DIM + c_l);
      p += acc[i][j].x * wd.x + acc[i][j].y * wd.y + acc[i][j].z * wd.z +
           acc[i][j].w * wd.w;
    }
    p += __shfl_xor(p, 16, 64);
    p += __shfl_xor(p, 32, 64);
    if (q == 0) atomicAdd(&out[(size_t)mt * N_DIM + n_g], p);
  }
}

extern "C" void kernel_launch(void* const* d_in, const int* in_sizes, int n_in,
                              void* d_out, int out_size, void* d_ws, size_t ws_size,
                              hipStream_t stream) {
  const float* x = (const float*)d_in[0];
  const float* Ws = (const float*)d_in[1];
  const float* Wd = (const float*)d_in[2];
  const float* Wb = (const float*)d_in[3];
  float* out = (float*)d_out;
  short* wsbf = (short*)d_ws;  // [WS_ELEMS] bf16 W_s only

  convert_ws_bias<<<dim3(WSBLK + 128), dim3(256), 0, stream>>>(Ws, Wb, wsbf, out);
  gemm_fused<<<dim3(32 * 8 * 2), dim3(512), 0, stream>>>(x, wsbf, Wd, out);
}

// Round 13
// 211.094 us; speedup vs baseline: 1.1021x; 1.1021x over previous
//
#include <hip/hip_runtime.h>
#include <stdint.h>

// out[b,n] = sum_{c,hw} x[b,c,hw]*W_s[n,hw]*W_d[n,c] + W_b[n]
// GEMM: A = x (M=8192, K=3136), B = W_s (N=1024, K=3136), fused c-contraction.
// R12: producer-consumer wave specialization. 8-wave blocks: waves 4-7 DMA
//      A+B tiles into a 3-slot LDS ring (no __syncthreads in K-loop; slots
//      flagged via LDS atomics after wave-local s_waitcnt), waves 0-3 MFMA
//      (wave tile 128x64). Tile 256x128 (bytes-optimal 602 MB ingest), grid
//      256 = 1 block/CU. Evidence: gemm dur == DMA bytes / rate in ALL prior
//      rounds; rate ceiling ~13.8 TB/s needs staging/compute overlap that the
//      2-barrier structure can't express at 602 MB.

#define K_DIM 3136
#define N_DIM 1024
#define C_DIM 256
#define B_DIM 32
#define M_DIM 8192
#define X_ELEMS (M_DIM * K_DIM)   // 25690112
#define WS_ELEMS (N_DIM * K_DIM)  // 3211264
#define SLOT_BYTES 49152          // A 32 KB + B 16 KB
#define NSLOT 3

typedef __attribute__((ext_vector_type(8))) short short8v;  // 8 bf16
typedef __attribute__((ext_vector_type(4))) float f32x4;

__device__ __forceinline__ short f2bf(float f) {
  union { float f; unsigned u; } v; v.f = f;
  unsigned r = v.u + 0x7FFFu + ((v.u >> 16) & 1u);
  return (short)(r >> 16);
}

// 16B-per-lane async global->LDS. LDS dest = wave-uniform base + lane*16.
__device__ __forceinline__ void async16(const void* g, void* l) {
  __builtin_amdgcn_global_load_lds(
      (const __attribute__((address_space(1))) unsigned int*)g,
      (__attribute__((address_space(3))) unsigned int*)l, 16, 0, 0);
}

// fp32 -> bf16 for x and W_s (16 elems/thread), plus bias into out.
#define XBLK (X_ELEMS / 4096)                 // 6272
#define CVBLK ((X_ELEMS + WS_ELEMS) / 4096)   // 7056
__global__ __launch_bounds__(256) void convert_bf16_bias(
    const float* __restrict__ x, const float* __restrict__ Ws,
    const float* __restrict__ Wb, short* __restrict__ dst,
    float* __restrict__ out) {
  int bid = blockIdx.x;
  if (bid >= CVBLK) {  // bias: 32768 out elems / 256 = 128 blocks
    int i = (bid - CVBLK) * 256 + threadIdx.x;
    out[i] = Wb[i & (N_DIM - 1)];
    return;
  }
  const float* src;
  short* d;
  size_t base;
  if (bid < XBLK) {
    src = x; d = dst; base = (size_t)bid * 4096;
  } else {
    src = Ws; d = dst + X_ELEMS; base = (size_t)(bid - XBLK) * 4096;
  }
#pragma unroll
  for (int h = 0; h < 2; ++h) {
    size_t i = base + threadIdx.x * 8 + h * 2048;
    f32x4 v0 = __builtin_nontemporal_load((const f32x4*)(src + i));
    f32x4 v1 = __builtin_nontemporal_load((const f32x4*)(src + i) + 1);
    short8v s;
    s[0] = f2bf(v0.x); s[1] = f2bf(v0.y); s[2] = f2bf(v0.z); s[3] = f2bf(v0.w);
    s[4] = f2bf(v1.x); s[5] = f2bf(v1.y); s[6] = f2bf(v1.z); s[7] = f2bf(v1.w);
    *(short8v*)(d + i) = s;
  }
}

// Slot layout: A = 256 rows x 8 chunks (16 B), slot(row,cs) holds chunk
// cs ^ (row&7) (verified conflict-free R1..R11); B = 128 rows x 8 chunks,
// same swizzle. Ring of 3 slots, LDS-atomic flags, no K-loop barriers.
__global__ __launch_bounds__(512, 2) void gemm_fused(
    const short* __restrict__ Abf, const short* __restrict__ Bbf,
    const float* __restrict__ Wd, float* __restrict__ out) {
  __shared__ __align__(16) char ring[NSLOT * SLOT_BYTES];  // 144 KB
  __shared__ int prod_cnt[NSLOT];
  __shared__ int cons_cnt[NSLOT];

  const int bid = blockIdx.x;
  const int mt = bid & 31;          // bid%8 == mt%8 -> A-tile pinned to XCD
  const int nt = bid >> 5;          // 0..7
  const int KT = 49;                // K tiles of 64 (no split; 1 block/CU)

  const int t = threadIdx.x;
  const int lane = t & 63;
  const int wv = t >> 6;            // 0..7: 0-3 consume, 4-7 produce
  const int lr = lane & 15;
  const int q = lane >> 4;

  if (t < NSLOT) { prod_cnt[t] = 0; cons_cnt[t] = 0; }
  __syncthreads();  // flag init visible (only barrier in the kernel)

  if (wv >= 4) {
    // ---------------- producer waves ----------------
    const int p = wv - 4;           // 0..3
    const int rr = lane >> 3;       // row within 8-row group
    const int k8 = (lane & 7) ^ rr; // swizzled chunk for this slot
    const short* Aw = Abf + (size_t)(mt * 256 + p * 64 + rr) * K_DIM + k8 * 8;
    const short* Bw = Bbf + (size_t)(nt * 128 + p * 32 + rr) * K_DIM + k8 * 8;
    for (int kt = 0; kt < KT; ++kt) {
      const int s = kt % NSLOT;
      const int r = kt / NSLOT;
      if (r > 0) {  // wait until all 4 consumers released this slot
        volatile int* cc = cons_cnt;
        while (cc[s] < 4 * r) {}
      }
      char* As_s = ring + s * SLOT_BYTES;
      char* Bs_s = As_s + 32768;
#pragma unroll
      for (int i = 0; i < 8; ++i)
        async16(Aw + (size_t)i * 8 * K_DIM + kt * 64,
                As_s + p * 8192 + i * 1024);
#pragma unroll
      for (int i = 0; i < 4; ++i)
        async16(Bw + (size_t)i * 8 * K_DIM + kt * 64,
                Bs_s + p * 4096 + i * 1024);
      __builtin_amdgcn_s_waitcnt(0);      // wave-local: this wave's DMA done
      __builtin_amdgcn_sched_barrier(0);  // pin flag after the wait
      if (lane == 0) atomicAdd(&prod_cnt[s], 1);
    }
    return;  // producers exit; consumers still computing (no barrier needed)
  }

  // ---------------- consumer waves ----------------
  const int wm = wv >> 1, wn = wv & 1;  // 2x2 grid; wave tile 128x64
  f32x4 acc[8][4];
#pragma unroll
  for (int i = 0; i < 8; ++i)
#pragma unroll
    for (int j = 0; j < 4; ++j) acc[i][j] = (f32x4)0.0f;

  for (int kt = 0; kt < KT; ++kt) {
    const int s = kt % NSLOT;
    const int r = kt / NSLOT;
    {
      volatile int* pc = prod_cnt;
      while (pc[s] < 4 * (r + 1)) {}  // all 4 producers filled this slot
    }
    __builtin_amdgcn_sched_barrier(0);
    const char* As_s = ring + s * SLOT_BYTES;
    const char* Bs_s = As_s + 32768;
#pragma unroll
    for (int ks = 0; ks < 2; ++ks) {
      const int xo = ((ks * 4 + q) ^ (lr & 7)) * 16;
      short8v b[4];
#pragma unroll
      for (int j = 0; j < 4; ++j)
        b[j] = *(const short8v*)(Bs_s + (64 * wn + 16 * j + lr) * 128 + xo);
#pragma unroll
      for (int i = 0; i < 8; ++i) {
        short8v a = *(const short8v*)(As_s + (128 * wm + 16 * i + lr) * 128 + xo);
#pragma unroll
        for (int j = 0; j < 4; ++j)
          acc[i][j] = __builtin_amdgcn_mfma_f32_16x16x32_bf16(a, b[j],
                                                              acc[i][j], 0, 0, 0);
      }
    }
    __builtin_amdgcn_s_waitcnt(0);      // all ds_reads of this slot returned
    __builtin_amdgcn_sched_barrier(0);
    if (lane == 0) atomicAdd(&cons_cnt[s], 1);
  }

  // epilogue: out[mt, n] += sum_c acc * W_d[n, c]; A-tile = image mt, c = row.
  // C/D frag layout: col = lane&15 (n), row = q*4 + reg (c). (verified R6)
#pragma unroll
  for (int j = 0; j < 4; ++j) {
    const int n_g = nt * 128 + 64 * wn + 16 * j + lr;
    float p = 0.0f;
#pragma unroll
    for (int i = 0; i < 8; ++i) {
      const int c_l = 128 * wm + 16 * i + 4 * q;
      const float4 wd = *(const float4*)(Wd + (size_t)n_g * C_DIM + c_l);
      p += acc[i][j].x * wd.x + acc[i][j].y * wd.y + acc[i][j].z * wd.z +
           acc[i][j].w * wd.w;
    }
    p += __shfl_xor(p, 16, 64);
    p += __shfl_xor(p, 32, 64);
    if (q == 0) atomicAdd(&out[(size_t)mt * N_DIM + n_g], p);
  }
}

extern "C" void kernel_launch(void* const* d_in, const int* in_sizes, int n_in,
                              void* d_out, int out_size, void* d_ws, size_t ws_size,
                              hipStream_t stream) {
  const float* x = (const float*)d_in[0];
  const float* Ws = (const float*)d_in[1];
  const float* Wd = (const float*)d_in[2];
  const float* Wb = (const float*)d_in[3];
  float* out = (float*)d_out;
  short* xbf = (short*)d_ws;  // [X_ELEMS] bf16 x, then [WS_ELEMS] bf16 W_s

  convert_bf16_bias<<<dim3(CVBLK + 128), dim3(256), 0, stream>>>(x, Ws, Wb, xbf, out);
  gemm_fused<<<dim3(32 * 8), dim3(512), 0, stream>>>(xbf, xbf + X_ELEMS, Wd, out);
}